// Round 17
// baseline (134.673 us; speedup 1.0000x reference)
//
#include <hip/hip_runtime.h>
#include <hip/hip_bf16.h>

#define EMBED 1024
#define HEADS 16
#define HDIM 64
#define BATCH 2
#define SEQ 2048
#define MTOT (BATCH*SEQ)

typedef __attribute__((ext_vector_type(2))) float f32x2;
typedef __attribute__((ext_vector_type(4))) float f32x4;
typedef __attribute__((ext_vector_type(16))) float f32x16;
typedef __attribute__((ext_vector_type(4))) short s16x4;
typedef __attribute__((ext_vector_type(8))) short bf16x8;
typedef __attribute__((ext_vector_type(4))) int i32x4;

static __device__ __forceinline__ short f2bf(float f) {
  unsigned u = __builtin_bit_cast(unsigned, f);
  unsigned r = (u + 0x7fffu + ((u >> 16) & 1u)) >> 16;
  return (short)r;
}
static __device__ __forceinline__ float bf2f(short s) {
  unsigned u = ((unsigned)(unsigned short)s) << 16;
  return __builtin_bit_cast(float, u);
}
// Fast bf16 pair pack: integer prebias (+0x8000 = round-half-up, ~RTNE) then
// hw truncating v_cvt_pk_bf16_f32. (Plain cvt_pk = 1-ulp one-sided
// truncation -> failed R3.)
static __device__ __forceinline__ int pack2bf_fast(float lo, float hi) {
  unsigned ulo = __builtin_bit_cast(unsigned, lo) + 0x8000u;
  unsigned uhi = __builtin_bit_cast(unsigned, hi) + 0x8000u;
  int r;
  asm("v_cvt_pk_bf16_f32 %0, %1, %2" : "=v"(r)
      : "v"(__builtin_bit_cast(float, ulo)), "v"(__builtin_bit_cast(float, uhi)));
  return r;
}

typedef __attribute__((address_space(1))) const void gvoid_t;
typedef __attribute__((address_space(3))) void lvoid_t;
static __device__ __forceinline__ void gload_lds16(const void* g, void* l) {
  __builtin_amdgcn_global_load_lds((gvoid_t*)g, (lvoid_t*)l, 16, 0, 0);
}

// ---------------------------------------------------------------------------
// One-shot fp32 -> bf16 conversion of x + 4 weights, plus RoPE cos/sin table.
// ---------------------------------------------------------------------------
__global__ __launch_bounds__(256) void cvt_bf16(
    const float* __restrict__ x,
    const float* __restrict__ Wq, const float* __restrict__ Wk,
    const float* __restrict__ Wv, const float* __restrict__ Wo,
    short* __restrict__ xb,
    short* __restrict__ Wqb, short* __restrict__ Wkb,
    short* __restrict__ Wvb, short* __restrict__ Wob,
    f32x2* __restrict__ tab)
{
  int i = blockIdx.x * 256 + threadIdx.x;     // < 2,097,152 + 65,536
  if (i >= 2097152) {
    int i2 = i - 2097152;                     // < 65536
    int t = i2 >> 5, j = i2 & 31;
    float invf = exp2f(-(float)j * 0.4152410118609203f);   // log2(10000)/32
    float sn, cs;
    sincosf((float)t * invf, &sn, &cs);
    f32x2 e; e[0] = cs; e[1] = sn;
    tab[i2] = e;
    return;
  }
  const float* src; short* dst; int off;
  if (i < 1048576) { src = x; dst = xb; off = i; }
  else {
    int j = i - 1048576;
    int w = j >> 18; off = j & 262143;
    src = (w == 0) ? Wq : (w == 1) ? Wk : (w == 2) ? Wv : Wo;
    dst = (w == 0) ? Wqb : (w == 1) ? Wkb : (w == 2) ? Wvb : Wob;
  }
  f32x4 v = ((const f32x4*)src)[off];
  s16x4 h;
#pragma unroll
  for (int j = 0; j < 4; ++j) h[j] = f2bf(v[j]);
  ((s16x4*)dst)[off] = h;
}

// ---------------------------------------------------------------------------
// Fused QKV projection (R14 form: single-buffered BK=64 + XOR chunk-swizzle,
// 32 KB LDS = 3 blocks/CU; R15's dbuf cost a residency slot for ~no gain).
// Table RoPE epilogue; swapped-operand V for contiguous V^T stores.
// ---------------------------------------------------------------------------
__global__ __launch_bounds__(256) void qkv_gemm(
    const short* __restrict__ xb,
    const short* __restrict__ Wqb, const short* __restrict__ Wkb, const short* __restrict__ Wvb,
    const float* __restrict__ bq, const float* __restrict__ bk, const float* __restrict__ bv,
    const f32x2* __restrict__ tab,
    short* __restrict__ Qb, short* __restrict__ Kb, short* __restrict__ Vb)
{
  __shared__ short As[128][64];
  __shared__ short Bs[128][64];
  int tid = threadIdx.x;
  int lane = tid & 63, wid = tid >> 6;
  int wm = wid >> 1, wn = wid & 1;
  int bm = blockIdx.x / 24;
  int bncol = blockIdx.x % 24;
  int wsel = bncol >> 3, bnn = bncol & 7;
  const short* W    = (wsel == 0) ? Wqb : (wsel == 1) ? Wkb : Wvb;
  const float* bias = (wsel == 0) ? bq : (wsel == 1) ? bk : bv;

  f32x4 acc[4][4] = {};

  const short* Abase = xb + (size_t)bm * 128 * EMBED;
  const short* Bbase = W + (size_t)bnn * 128 * EMBED;
  char* AsB = (char*)&As[0][0];
  char* BsB = (char*)&Bs[0][0];

  for (int kt = 0; kt < EMBED / 64; ++kt) {
#pragma unroll
    for (int i = 0; i < 4; ++i) {
      int s = tid + i * 256;           // 1024 16B-chunks per tile
      int row = s >> 3, c = s & 7;
      int cs = c ^ (row & 7);          // inverse-swizzled source chunk
      gload_lds16(&Abase[(size_t)row * EMBED + kt * 64 + cs * 8],
                  AsB + i * 4096 + wid * 1024 + lane * 16);
      gload_lds16(&Bbase[(size_t)row * EMBED + kt * 64 + cs * 8],
                  BsB + i * 4096 + wid * 1024 + lane * 16);
    }
    __syncthreads();
#pragma unroll
    for (int kk = 0; kk < 2; ++kk) {
      int cp = ((kk * 4 + (lane >> 4)) ^ (lane & 7)) * 8;   // swizzled read col
      bf16x8 af[4], bfr[4];
#pragma unroll
      for (int mf = 0; mf < 4; ++mf)
        af[mf] = *(const bf16x8*)&As[wm * 64 + mf * 16 + (lane & 15)][cp];
#pragma unroll
      for (int nf = 0; nf < 4; ++nf)
        bfr[nf] = *(const bf16x8*)&Bs[wn * 64 + nf * 16 + (lane & 15)][cp];
      if (wsel == 2) {
        // swapped operands: D[reg -> W-row(channel)][lane -> x-row(token)]
#pragma unroll
        for (int mf = 0; mf < 4; ++mf)
#pragma unroll
          for (int nf = 0; nf < 4; ++nf)
            acc[mf][nf] = __builtin_amdgcn_mfma_f32_16x16x32_bf16(bfr[mf], af[nf], acc[mf][nf], 0, 0, 0);
      } else {
#pragma unroll
        for (int mf = 0; mf < 4; ++mf)
#pragma unroll
          for (int nf = 0; nf < 4; ++nf)
            acc[mf][nf] = __builtin_amdgcn_mfma_f32_16x16x32_bf16(af[mf], bfr[nf], acc[mf][nf], 0, 0, 0);
      }
    }
    __syncthreads();
  }

  if (wsel < 2) {
    short* dst = (wsel == 0) ? Qb : Kb;
    // Q scale folds 1/sqrt(D) AND log2(e) so softmax is a bare exp2.
    float sc = (wsel == 0) ? 0.18033688011112042f : 1.0f;
#pragma unroll
    for (int nf = 0; nf < 2; ++nf) {
      int col = bnn * 128 + wn * 64 + nf * 16 + (lane & 15);  // d = col&63 in [0,32)
      int h = col >> 6, j = col & 31;
      float b1 = bias[col], b2 = bias[col + 32];
#pragma unroll
      for (int mf = 0; mf < 4; ++mf) {
        int row0 = bm * 128 + wm * 64 + mf * 16 + ((lane >> 4) << 2);
#pragma unroll
        for (int r = 0; r < 4; ++r) {
          int m = row0 + r;
          int b_ = m >> 11, t = m & (SEQ - 1);
          f32x2 e = tab[t * 32 + j];     // {cos, sin}
          float a1 = acc[mf][nf][r] + b1;
          float a2 = acc[mf][nf + 2][r] + b2;
          size_t o = (((size_t)(b_ * HEADS + h)) * SEQ + t) * HDIM + j;
          dst[o]      = f2bf((a1 * e[0] - a2 * e[1]) * sc);
          dst[o + 32] = f2bf((a2 * e[0] + a1 * e[1]) * sc);
        }
      }
    }
  } else {
    // V transposed store, swapped-accumulator layout (lane dim = token).
#pragma unroll
    for (int mf = 0; mf < 4; ++mf) {
#pragma unroll
      for (int r = 0; r < 4; ++r) {
        int cch = bnn * 128 + wn * 64 + mf * 16 + ((lane >> 4) << 2) + r;
        int h = cch >> 6, d = cch & 63;
        float bb = bias[cch];
#pragma unroll
        for (int nf = 0; nf < 4; ++nf) {
          int m = bm * 128 + wm * 64 + nf * 16 + (lane & 15);
          int b_ = m >> 11, t = m & (SEQ - 1);
          Vb[((size_t)(b_ * HEADS + h) * HDIM + d) * SEQ + t] = f2bf(acc[mf][nf][r] + bb);
        }
      }
    }
  }
}

// ---------------------------------------------------------------------------
// Flash attention — 16-q-row waves via 16x16x32 MFMA (qkv-verified fragment
// conventions), KEY-PERMUTED QK so P is fully lane-local for PV (zero
// cross-lane ops): QK A-row m <- key 8*(m>>2)+4*kb+(m&3), giving lane-group g
// ownership of keys 8g..8g+7 per 32-chunk = exactly PV's B-fragment rows.
// Key order is softmax- and contraction-invariant. QBLK=64, 4 waves x 16 q,
// grid 1024 = 4 blocks/CU = 16 waves/CU (2x the 32-q structure's cap).
// dbuf single-barrier staging (R14-proven); epilogue coalesced via LDS.
// ---------------------------------------------------------------------------
#define QBLK 64
#define KBLK 64

__global__ __launch_bounds__(256, 4) void attn_kernel(
    const short* __restrict__ Qb, const short* __restrict__ Kb,
    const short* __restrict__ Vb, short* __restrict__ Ob)
{
  __shared__ short Ks[2][KBLK][68];   // stride 136B -> 2-way (free)
  __shared__ short Vs[2][HDIM][68];   // V^T: Vs[buf][d][key]

  int tid = threadIdx.x, lane = tid & 63, wid = tid >> 6;
  int l15 = lane & 15, lg = lane >> 4;   // lane-group g in [0,4)

  // Bijective XCD swizzle: 1024 blocks -> 8 chunks of 128.
  int bid = blockIdx.x;
  int swz = (bid & 7) * 128 + (bid >> 3);
  int qi = swz & 31, bh = swz >> 5;
  int b = bh >> 4, h = bh & 15;

  const short* Qp = Qb + ((size_t)bh * SEQ + qi * QBLK + wid * 16) * HDIM;
  const short* Kp = Kb + (size_t)bh * SEQ * HDIM;
  const short* Vp = Vb + (size_t)bh * HDIM * SEQ;   // (d, t)

  // Q fragments (B-operand): B[k = lg*8+j][col = q = l15], k-chunks ec=0,1
  bf16x8 qf[2];
#pragma unroll
  for (int ec = 0; ec < 2; ++ec)
    qf[ec] = *(const bf16x8*)&Qp[(size_t)l15 * HDIM + ec * 32 + lg * 8];

  f32x4 oacc[4] = {};   // O^T[d-frag df][.]: row d=df*16+4*lg+r, col q=l15
  f32x4 lacc = {};
  bf16x8 vones;
#pragma unroll
  for (int j = 0; j < 8; ++j) vones[j] = (short)0x3F80;  // bf16 1.0

  // QK A-row permutation base: A-row m=l15 <- key 8*(m>>2) + 4*kb + (m&3)
  int arow = 8 * (l15 >> 2) + (l15 & 3);

  // prefetch tile 0 into regs: K 64x64 (512 slots), V 64x64 (512 slots)
  bf16x8 kreg[2], vreg[2];
#pragma unroll
  for (int i = 0; i < 2; ++i) {
    int s = tid + i * 256;
    kreg[i] = *(const bf16x8*)&Kp[(size_t)(s >> 3) * HDIM + (s & 7) * 8];
    vreg[i] = *(const bf16x8*)&Vp[(size_t)(s >> 3) * SEQ + (s & 7) * 8];
  }
  // stage tile 0 into buf 0
#pragma unroll
  for (int i = 0; i < 2; ++i) {
    int s = tid + i * 256;
    *(bf16x8*)&Ks[0][s >> 3][(s & 7) * 8] = kreg[i];
    *(bf16x8*)&Vs[0][s >> 3][(s & 7) * 8] = vreg[i];
  }
  __syncthreads();

  for (int kt = 0; kt < SEQ / KBLK; ++kt) {
    int cur = kt & 1;
    // issue global loads for tile kt+1 (latency hides under compute below)
    if (kt + 1 < SEQ / KBLK) {
#pragma unroll
      for (int i = 0; i < 2; ++i) {
        int s = tid + i * 256;
        kreg[i] = *(const bf16x8*)&Kp[(size_t)((kt + 1) * KBLK + (s >> 3)) * HDIM + (s & 7) * 8];
        vreg[i] = *(const bf16x8*)&Vp[(size_t)(s >> 3) * SEQ + (kt + 1) * KBLK + (s & 7) * 8];
      }
    }

#pragma unroll
    for (int kc = 0; kc < 2; ++kc) {       // two 32-key chunks per tile
      // QK: S^T[key][q]; lane owns keys kc*32 + 8*lg + 4*kb + r
      f32x4 s0 = {}, s1 = {};
#pragma unroll
      for (int ec = 0; ec < 2; ++ec) {
        bf16x8 a0 = *(const bf16x8*)&Ks[cur][kc * 32 + 0 + arow][ec * 32 + lg * 8];
        bf16x8 a1 = *(const bf16x8*)&Ks[cur][kc * 32 + 4 + arow][ec * 32 + lg * 8];
        s0 = __builtin_amdgcn_mfma_f32_16x16x32_bf16(a0, qf[ec], s0, 0, 0, 0);
        s1 = __builtin_amdgcn_mfma_f32_16x16x32_bf16(a1, qf[ec], s1, 0, 0, 0);
      }
      // p = exp2(s'); then B-frag k = 8*lg + j: j0..3 <- kb0, j4..7 <- kb1
      float p0[4], p1[4];
#pragma unroll
      for (int r = 0; r < 4; ++r) {
        p0[r] = __builtin_amdgcn_exp2f(s0[r]);
        p1[r] = __builtin_amdgcn_exp2f(s1[r]);
      }
      i32x4 pw;
      pw[0] = pack2bf_fast(p0[0], p0[1]);
      pw[1] = pack2bf_fast(p0[2], p0[3]);
      pw[2] = pack2bf_fast(p1[0], p1[1]);
      pw[3] = pack2bf_fast(p1[2], p1[3]);
      bf16x8 pa = __builtin_bit_cast(bf16x8, pw);

      // PV: O^T[d][q] += V^T[d][key] * P[key][q]; A=V^T frag, B=pa
#pragma unroll
      for (int df = 0; df < 4; ++df) {
        bf16x8 vf = *(const bf16x8*)&Vs[cur][df * 16 + l15][kc * 32 + lg * 8];
        oacc[df] = __builtin_amdgcn_mfma_f32_16x16x32_bf16(vf, pa, oacc[df], 0, 0, 0);
      }
      lacc = __builtin_amdgcn_mfma_f32_16x16x32_bf16(vones, pa, lacc, 0, 0, 0);
    }

    // stage tile kt+1 into the other buffer, then single barrier
    if (kt + 1 < SEQ / KBLK) {
#pragma unroll
      for (int i = 0; i < 2; ++i) {
        int s = tid + i * 256;
        *(bf16x8*)&Ks[cur ^ 1][s >> 3][(s & 7) * 8] = kreg[i];
        *(bf16x8*)&Vs[cur ^ 1][s >> 3][(s & 7) * 8] = vreg[i];
      }
      __syncthreads();
    }
  }

  // epilogue: O^T is lane-scattered; round-trip through LDS for coalescing.
  __syncthreads();                          // all compute reads of Ks/Vs done
  short (*Os)[68] = (short(*)[68])&Ks[0][0][0];   // [64 q][64 d] staging
  float inv = 1.0f / lacc[0];               // all rows of lacc equal l_q
  int qrow = wid * 16 + l15;
#pragma unroll
  for (int df = 0; df < 4; ++df) {
    int d0 = df * 16 + 4 * lg;
    *(int*)&Os[qrow][d0]     = pack2bf_fast(oacc[df][0] * inv, oacc[df][1] * inv);
    *(int*)&Os[qrow][d0 + 2] = pack2bf_fast(oacc[df][2] * inv, oacc[df][3] * inv);
  }
  __syncthreads();
#pragma unroll
  for (int i = 0; i < 2; ++i) {
    int s = tid + i * 256;                  // 512 bf16x8 slots (64 x 64)
    int qr = s >> 3, c8 = (s & 7) * 8;
    int t = qi * QBLK + qr;
    bf16x8 v = *(const bf16x8*)&Os[qr][c8];
    *(bf16x8*)&Ob[((size_t)(b * SEQ + t)) * EMBED + h * HDIM + c8] = v;
  }
}

// ---------------------------------------------------------------------------
// Output projection, 64x128 tile, BK=64 + XOR chunk-swizzle, double-buffered
// single-barrier loop. LDS 48 KB (grid 512 = 2 blocks/CU, unaffected).
// ---------------------------------------------------------------------------
__global__ __launch_bounds__(256) void out_gemm(
    const short* __restrict__ A, const short* __restrict__ Wob,
    const float* __restrict__ bo, float* __restrict__ C)
{
  __shared__ short As[2][64][64];    // 2 x 8 KB
  __shared__ short Bs[2][128][64];   // 2 x 16 KB
  int tid = threadIdx.x;
  int lane = tid & 63, wid = tid >> 6;
  int bm = blockIdx.x >> 3, bn = blockIdx.x & 7;   // 64 x 8

  f32x4 acc[8] = {};
  const short* Abase = A + (size_t)bm * 64 * EMBED;
  const short* Bbase = Wob + (size_t)bn * 128 * EMBED;
  char* AsB = (char*)&As[0][0][0];
  char* BsB = (char*)&Bs[0][0][0];
  const int ATSZ = 64 * 64 * 2;      // 8192 B
  const int BTSZ = 128 * 64 * 2;     // 16384 B

  // prologue: stage tile 0 into buffer 0
#pragma unroll
  for (int i = 0; i < 2; ++i) {
    int s = tid + i * 256;           // 512 chunks (A tile 64x64)
    int row = s >> 3, c = s & 7;
    int cs = c ^ (row & 7);
    gload_lds16(&Abase[(size_t)row * EMBED + cs * 8],
                AsB + i * 4096 + wid * 1024 + lane * 16);
  }
#pragma unroll
  for (int i = 0; i < 4; ++i) {
    int s = tid + i * 256;           // 1024 chunks (B tile 128x64)
    int row = s >> 3, c = s & 7;
    int cs = c ^ (row & 7);
    gload_lds16(&Bbase[(size_t)row * EMBED + cs * 8],
                BsB + i * 4096 + wid * 1024 + lane * 16);
  }
  __syncthreads();

  for (int kt = 0; kt < EMBED / 64; ++kt) {
    int cur = kt & 1;
    if (kt + 1 < EMBED / 64) {
#pragma unroll
      for (int i = 0; i < 2; ++i) {
        int s = tid + i * 256;
        int row = s >> 3, c = s & 7;
        int cs = c ^ (row & 7);
        gload_lds16(&Abase[(size_t)row * EMBED + (kt + 1) * 64 + cs * 8],
                    AsB + (cur ^ 1) * ATSZ + i * 4096 + wid * 1024 + lane * 16);
      }
#pragma unroll
      for (int i = 0; i < 4; ++i) {
        int s = tid + i * 256;
        int row = s >> 3, c = s & 7;
        int cs = c ^ (row & 7);
        gload_lds16(&Bbase[(size_t)row * EMBED + (kt + 1) * 64 + cs * 8],
                    BsB + (cur ^ 1) * BTSZ + i * 4096 + wid * 1024 + lane * 16);
      }
    }

#pragma unroll
    for (int kk = 0; kk < 2; ++kk) {
      int cp = ((kk * 4 + (lane >> 4)) ^ (lane & 7)) * 8;
      bf16x8 af = *(const bf16x8*)&As[cur][wid * 16 + (lane & 15)][cp];
#pragma unroll
      for (int nf = 0; nf < 8; ++nf) {
        bf16x8 bfr = *(const bf16x8*)&Bs[cur][nf * 16 + (lane & 15)][cp];
        acc[nf] = __builtin_amdgcn_mfma_f32_16x16x32_bf16(af, bfr, acc[nf], 0, 0, 0);
      }
    }
    __syncthreads();
  }

#pragma unroll
  for (int nf = 0; nf < 8; ++nf) {
    int col = bn * 128 + nf * 16 + (lane & 15);
    float bb = bo[col];
    int row0 = bm * 64 + wid * 16 + ((lane >> 4) << 2);
#pragma unroll
    for (int r = 0; r < 4; ++r)
      C[(size_t)(row0 + r) * EMBED + col] = acc[nf][r] + bb;
  }
}

extern "C" void kernel_launch(void* const* d_in, const int* in_sizes, int n_in,
                              void* d_out, int out_size, void* d_ws, size_t ws_size,
                              hipStream_t stream) {
  const float* x  = (const float*)d_in[0];
  const float* Wq = (const float*)d_in[1];
  const float* bq = (const float*)d_in[2];
  const float* Wk = (const float*)d_in[3];
  const float* bk = (const float*)d_in[4];
  const float* Wv = (const float*)d_in[5];
  const float* bv = (const float*)d_in[6];
  const float* Wo = (const float*)d_in[7];
  const float* bo = (const float*)d_in[8];
  float* out = (float*)d_out;
  char* ws = (char*)d_ws;

  const size_t MB = 1u << 20;
  short* Qb  = (short*)(ws);                 // 8 MiB
  short* Kb  = (short*)(ws + 8 * MB);        // 8 MiB
  short* Vb  = (short*)(ws + 16 * MB);       // 8 MiB
  short* XOb = (short*)(ws + 24 * MB);       // 8 MiB: xb during proj, Ob after attn
  short* Wqb = (short*)(ws + 32 * MB);
  short* Wkb = (short*)(ws + 34 * MB);
  short* Wvb = (short*)(ws + 36 * MB);
  short* Wob = (short*)(ws + 38 * MB);
  f32x2* tab = (f32x2*)(ws + 40 * MB);       // 512 KiB RoPE table

  cvt_bf16<<<dim3(8448), dim3(256), 0, stream>>>(x, Wq, Wk, Wv, Wo, XOb, Wqb, Wkb, Wvb, Wob, tab);
  qkv_gemm<<<dim3(32 * 24), dim3(256), 0, stream>>>(XOb, Wqb, Wkb, Wvb, bq, bk, bv, tab, Qb, Kb, Vb);
  attn_kernel<<<dim3(BATCH * HEADS * (SEQ / QBLK)), dim3(256), 0, stream>>>(Qb, Kb, Vb, XOb);
  out_gemm<<<dim3(64 * 8), dim3(256), 0, stream>>>(XOb, Wob, bo, out);
}

// Round 18
// 117.047 us; speedup vs baseline: 1.1506x; 1.1506x over previous
//
#include <hip/hip_runtime.h>
#include <hip/hip_bf16.h>

#define EMBED 1024
#define HEADS 16
#define HDIM 64
#define BATCH 2
#define SEQ 2048
#define MTOT (BATCH*SEQ)

typedef __attribute__((ext_vector_type(2))) float f32x2;
typedef __attribute__((ext_vector_type(4))) float f32x4;
typedef __attribute__((ext_vector_type(16))) float f32x16;
typedef __attribute__((ext_vector_type(4))) short s16x4;
typedef __attribute__((ext_vector_type(8))) short bf16x8;
typedef __attribute__((ext_vector_type(4))) int i32x4;

static __device__ __forceinline__ short f2bf(float f) {
  unsigned u = __builtin_bit_cast(unsigned, f);
  unsigned r = (u + 0x7fffu + ((u >> 16) & 1u)) >> 16;
  return (short)r;
}
static __device__ __forceinline__ float bf2f(short s) {
  unsigned u = ((unsigned)(unsigned short)s) << 16;
  return __builtin_bit_cast(float, u);
}
// Fast bf16 pair pack: integer prebias (+0x8000 = round-half-up, ~RTNE) then
// hw truncating v_cvt_pk_bf16_f32. (Plain cvt_pk = 1-ulp one-sided
// truncation -> failed R3.)
static __device__ __forceinline__ int pack2bf_fast(float lo, float hi) {
  unsigned ulo = __builtin_bit_cast(unsigned, lo) + 0x8000u;
  unsigned uhi = __builtin_bit_cast(unsigned, hi) + 0x8000u;
  int r;
  asm("v_cvt_pk_bf16_f32 %0, %1, %2" : "=v"(r)
      : "v"(__builtin_bit_cast(float, ulo)), "v"(__builtin_bit_cast(float, uhi)));
  return r;
}
static __device__ __forceinline__ void pswap(int &a, int &b) {
  asm("v_permlane32_swap_b32 %0, %1" : "+v"(a), "+v"(b));
}

typedef __attribute__((address_space(1))) const void gvoid_t;
typedef __attribute__((address_space(3))) void lvoid_t;
static __device__ __forceinline__ void gload_lds16(const void* g, void* l) {
  __builtin_amdgcn_global_load_lds((gvoid_t*)g, (lvoid_t*)l, 16, 0, 0);
}

// ---------------------------------------------------------------------------
// One-shot fp32 -> bf16 conversion of x + 4 weights, plus RoPE cos/sin table.
// ---------------------------------------------------------------------------
__global__ __launch_bounds__(256) void cvt_bf16(
    const float* __restrict__ x,
    const float* __restrict__ Wq, const float* __restrict__ Wk,
    const float* __restrict__ Wv, const float* __restrict__ Wo,
    short* __restrict__ xb,
    short* __restrict__ Wqb, short* __restrict__ Wkb,
    short* __restrict__ Wvb, short* __restrict__ Wob,
    f32x2* __restrict__ tab)
{
  int i = blockIdx.x * 256 + threadIdx.x;     // < 2,097,152 + 65,536
  if (i >= 2097152) {
    int i2 = i - 2097152;                     // < 65536
    int t = i2 >> 5, j = i2 & 31;
    float invf = exp2f(-(float)j * 0.4152410118609203f);   // log2(10000)/32
    float sn, cs;
    sincosf((float)t * invf, &sn, &cs);
    f32x2 e; e[0] = cs; e[1] = sn;
    tab[i2] = e;
    return;
  }
  const float* src; short* dst; int off;
  if (i < 1048576) { src = x; dst = xb; off = i; }
  else {
    int j = i - 1048576;
    int w = j >> 18; off = j & 262143;
    src = (w == 0) ? Wq : (w == 1) ? Wk : (w == 2) ? Wv : Wo;
    dst = (w == 0) ? Wqb : (w == 1) ? Wkb : (w == 2) ? Wvb : Wob;
  }
  f32x4 v = ((const f32x4*)src)[off];
  s16x4 h;
#pragma unroll
  for (int j = 0; j < 4; ++j) h[j] = f2bf(v[j]);
  ((s16x4*)dst)[off] = h;
}

// ---------------------------------------------------------------------------
// Fused QKV projection (single-buffered BK=64 + XOR chunk-swizzle, 32 KB LDS
// = 3 blocks/CU). Table RoPE epilogue; swapped-operand V for contiguous V^T
// stores.
// ---------------------------------------------------------------------------
__global__ __launch_bounds__(256) void qkv_gemm(
    const short* __restrict__ xb,
    const short* __restrict__ Wqb, const short* __restrict__ Wkb, const short* __restrict__ Wvb,
    const float* __restrict__ bq, const float* __restrict__ bk, const float* __restrict__ bv,
    const f32x2* __restrict__ tab,
    short* __restrict__ Qb, short* __restrict__ Kb, short* __restrict__ Vb)
{
  __shared__ short As[128][64];
  __shared__ short Bs[128][64];
  int tid = threadIdx.x;
  int lane = tid & 63, wid = tid >> 6;
  int wm = wid >> 1, wn = wid & 1;
  int bm = blockIdx.x / 24;
  int bncol = blockIdx.x % 24;
  int wsel = bncol >> 3, bnn = bncol & 7;
  const short* W    = (wsel == 0) ? Wqb : (wsel == 1) ? Wkb : Wvb;
  const float* bias = (wsel == 0) ? bq : (wsel == 1) ? bk : bv;

  f32x4 acc[4][4] = {};

  const short* Abase = xb + (size_t)bm * 128 * EMBED;
  const short* Bbase = W + (size_t)bnn * 128 * EMBED;
  char* AsB = (char*)&As[0][0];
  char* BsB = (char*)&Bs[0][0];

  for (int kt = 0; kt < EMBED / 64; ++kt) {
#pragma unroll
    for (int i = 0; i < 4; ++i) {
      int s = tid + i * 256;           // 1024 16B-chunks per tile
      int row = s >> 3, c = s & 7;
      int cs = c ^ (row & 7);          // inverse-swizzled source chunk
      gload_lds16(&Abase[(size_t)row * EMBED + kt * 64 + cs * 8],
                  AsB + i * 4096 + wid * 1024 + lane * 16);
      gload_lds16(&Bbase[(size_t)row * EMBED + kt * 64 + cs * 8],
                  BsB + i * 4096 + wid * 1024 + lane * 16);
    }
    __syncthreads();
#pragma unroll
    for (int kk = 0; kk < 2; ++kk) {
      int cp = ((kk * 4 + (lane >> 4)) ^ (lane & 7)) * 8;   // swizzled read col
      bf16x8 af[4], bfr[4];
#pragma unroll
      for (int mf = 0; mf < 4; ++mf)
        af[mf] = *(const bf16x8*)&As[wm * 64 + mf * 16 + (lane & 15)][cp];
#pragma unroll
      for (int nf = 0; nf < 4; ++nf)
        bfr[nf] = *(const bf16x8*)&Bs[wn * 64 + nf * 16 + (lane & 15)][cp];
      if (wsel == 2) {
        // swapped operands: D[reg -> W-row(channel)][lane -> x-row(token)]
#pragma unroll
        for (int mf = 0; mf < 4; ++mf)
#pragma unroll
          for (int nf = 0; nf < 4; ++nf)
            acc[mf][nf] = __builtin_amdgcn_mfma_f32_16x16x32_bf16(bfr[mf], af[nf], acc[mf][nf], 0, 0, 0);
      } else {
#pragma unroll
        for (int mf = 0; mf < 4; ++mf)
#pragma unroll
          for (int nf = 0; nf < 4; ++nf)
            acc[mf][nf] = __builtin_amdgcn_mfma_f32_16x16x32_bf16(af[mf], bfr[nf], acc[mf][nf], 0, 0, 0);
      }
    }
    __syncthreads();
  }

  if (wsel < 2) {
    short* dst = (wsel == 0) ? Qb : Kb;
    // Q scale folds 1/sqrt(D) AND log2(e) so softmax is a bare exp2.
    float sc = (wsel == 0) ? 0.18033688011112042f : 1.0f;
#pragma unroll
    for (int nf = 0; nf < 2; ++nf) {
      int col = bnn * 128 + wn * 64 + nf * 16 + (lane & 15);  // d = col&63 in [0,32)
      int h = col >> 6, j = col & 31;
      float b1 = bias[col], b2 = bias[col + 32];
#pragma unroll
      for (int mf = 0; mf < 4; ++mf) {
        int row0 = bm * 128 + wm * 64 + mf * 16 + ((lane >> 4) << 2);
#pragma unroll
        for (int r = 0; r < 4; ++r) {
          int m = row0 + r;
          int b_ = m >> 11, t = m & (SEQ - 1);
          f32x2 e = tab[t * 32 + j];     // {cos, sin}
          float a1 = acc[mf][nf][r] + b1;
          float a2 = acc[mf][nf + 2][r] + b2;
          size_t o = (((size_t)(b_ * HEADS + h)) * SEQ + t) * HDIM + j;
          dst[o]      = f2bf((a1 * e[0] - a2 * e[1]) * sc);
          dst[o + 32] = f2bf((a2 * e[0] + a1 * e[1]) * sc);
        }
      }
    }
  } else {
    // V transposed store, swapped-accumulator layout (lane dim = token).
#pragma unroll
    for (int mf = 0; mf < 4; ++mf) {
#pragma unroll
      for (int r = 0; r < 4; ++r) {
        int cch = bnn * 128 + wn * 64 + mf * 16 + ((lane >> 4) << 2) + r;
        int h = cch >> 6, d = cch & 63;
        float bb = bias[cch];
#pragma unroll
        for (int nf = 0; nf < 4; ++nf) {
          int m = bm * 128 + wm * 64 + nf * 16 + (lane & 15);
          int b_ = m >> 11, t = m & (SEQ - 1);
          Vb[((size_t)(b_ * HEADS + h) * HDIM + d) * SEQ + t] = f2bf(acc[mf][nf][r] + bb);
        }
      }
    }
  }
}

// ---------------------------------------------------------------------------
// Flash attention — R14 byte-exact (best measured: 50.6 µs, conflicts 0).
// 32-q-row waves, swapped-QK 32x32 MFMA, kb-pair ILP, prebias cvt_pk pack,
// raw v_exp_f32, LDS dbuf single-barrier, no setprio.
// (16-q restructures closed: R8 no-parallelism-gain, R16 4-way LDS conflicts
// inherent to the permuted row set at any 16B-aligned stride.)
// ---------------------------------------------------------------------------
#define QBLK 128
#define KBLK 64

__global__ __launch_bounds__(256, 2) void attn_kernel(
    const short* __restrict__ Qb, const short* __restrict__ Kb,
    const short* __restrict__ Vb, short* __restrict__ Ob)
{
  __shared__ short Ks[2][KBLK][68];   // stride 136B -> 2-way (free)
  __shared__ short Vs[2][HDIM][68];   // V^T: Vs[buf][d][key]

  int tid = threadIdx.x, lane = tid & 63, wid = tid >> 6;
  int l31 = lane & 31, lhi = lane >> 5;

  // Bijective XCD swizzle: 512 blocks -> 8 chunks of 64 (4 heads per chunk).
  int bid = blockIdx.x;
  int swz = (bid & 7) * 64 + (bid >> 3);
  int qi = swz & 15, bh = swz >> 4;
  int b = bh >> 4, h = bh & 15;

  const short* Qp = Qb + ((size_t)bh * SEQ + qi * QBLK + wid * 32) * HDIM;
  const short* Kp = Kb + (size_t)bh * SEQ * HDIM;
  const short* Vp = Vb + (size_t)bh * HDIM * SEQ;   // (d, t)

  // Q fragments: B-operand, col=lane&31=q, k-chunk cc
  bf16x8 qf[4];
#pragma unroll
  for (int cc = 0; cc < 4; ++cc)
    qf[cc] = *(const bf16x8*)&Qp[(size_t)l31 * HDIM + cc * 16 + lhi * 8];

  f32x16 oacc0 = {}, oacc1 = {}, lacc = {};
  bf16x8 vones;
#pragma unroll
  for (int j = 0; j < 8; ++j) vones[j] = (short)0x3F80;  // bf16 1.0

  // prefetch tile 0 into regs: K 64x64 (512 slots), V 64x64 (512 slots)
  bf16x8 kreg[2], vreg[2];
#pragma unroll
  for (int i = 0; i < 2; ++i) {
    int s = tid + i * 256;
    kreg[i] = *(const bf16x8*)&Kp[(size_t)(s >> 3) * HDIM + (s & 7) * 8];
    vreg[i] = *(const bf16x8*)&Vp[(size_t)(s >> 3) * SEQ + (s & 7) * 8];
  }
  // stage tile 0 into buf 0
#pragma unroll
  for (int i = 0; i < 2; ++i) {
    int s = tid + i * 256;
    *(bf16x8*)&Ks[0][s >> 3][(s & 7) * 8] = kreg[i];
    *(bf16x8*)&Vs[0][s >> 3][(s & 7) * 8] = vreg[i];
  }
  __syncthreads();

  for (int kt = 0; kt < SEQ / KBLK; ++kt) {
    int cur = kt & 1;
    // issue global loads for tile kt+1 (latency hides under compute below)
    if (kt + 1 < SEQ / KBLK) {
#pragma unroll
      for (int i = 0; i < 2; ++i) {
        int s = tid + i * 256;
        kreg[i] = *(const bf16x8*)&Kp[(size_t)((kt + 1) * KBLK + (s >> 3)) * HDIM + (s & 7) * 8];
        vreg[i] = *(const bf16x8*)&Vp[(size_t)(s >> 3) * SEQ + (kt + 1) * KBLK + (s & 7) * 8];
      }
    }

    // compute tile kt from buf[cur]: one kb-pair (two 32-key blocks)
    f32x16 s0 = {}, s1 = {};
#pragma unroll
    for (int cc = 0; cc < 4; ++cc) {
      bf16x8 a0 = *(const bf16x8*)&Ks[cur][l31][cc * 16 + lhi * 8];
      bf16x8 a1 = *(const bf16x8*)&Ks[cur][32 + l31][cc * 16 + lhi * 8];
      s0 = __builtin_amdgcn_mfma_f32_32x32x16_bf16(a0, qf[cc], s0, 0, 0, 0);
      s1 = __builtin_amdgcn_mfma_f32_32x32x16_bf16(a1, qf[cc], s1, 0, 0, 0);
    }
    f32x16 p0, p1;
#pragma unroll
    for (int i = 0; i < 16; ++i) {
      p0[i] = __builtin_amdgcn_exp2f(s0[i]);
      p1[i] = __builtin_amdgcn_exp2f(s1[i]);
    }

    // keys [kt*64, +32)
#pragma unroll
    for (int c = 0; c < 2; ++c) {
      int w0 = pack2bf_fast(p0[8 * c + 0], p0[8 * c + 1]);
      int w1 = pack2bf_fast(p0[8 * c + 2], p0[8 * c + 3]);
      int w2 = pack2bf_fast(p0[8 * c + 4], p0[8 * c + 5]);
      int w3 = pack2bf_fast(p0[8 * c + 6], p0[8 * c + 7]);
      pswap(w0, w2);
      pswap(w1, w3);
      i32x4 pw; pw[0] = w0; pw[1] = w1; pw[2] = w2; pw[3] = w3;
      bf16x8 pa = __builtin_bit_cast(bf16x8, pw);

      bf16x8 vf0 = *(const bf16x8*)&Vs[cur][l31][c * 16 + lhi * 8];
      bf16x8 vf1 = *(const bf16x8*)&Vs[cur][32 + l31][c * 16 + lhi * 8];
      lacc = __builtin_amdgcn_mfma_f32_32x32x16_bf16(pa, vones, lacc, 0, 0, 0);
      oacc0 = __builtin_amdgcn_mfma_f32_32x32x16_bf16(pa, vf0, oacc0, 0, 0, 0);
      oacc1 = __builtin_amdgcn_mfma_f32_32x32x16_bf16(pa, vf1, oacc1, 0, 0, 0);
    }
    // keys [kt*64+32, +32)
#pragma unroll
    for (int c = 0; c < 2; ++c) {
      int w0 = pack2bf_fast(p1[8 * c + 0], p1[8 * c + 1]);
      int w1 = pack2bf_fast(p1[8 * c + 2], p1[8 * c + 3]);
      int w2 = pack2bf_fast(p1[8 * c + 4], p1[8 * c + 5]);
      int w3 = pack2bf_fast(p1[8 * c + 6], p1[8 * c + 7]);
      pswap(w0, w2);
      pswap(w1, w3);
      i32x4 pw; pw[0] = w0; pw[1] = w1; pw[2] = w2; pw[3] = w3;
      bf16x8 pa = __builtin_bit_cast(bf16x8, pw);

      bf16x8 vf0 = *(const bf16x8*)&Vs[cur][l31][32 + c * 16 + lhi * 8];
      bf16x8 vf1 = *(const bf16x8*)&Vs[cur][32 + l31][32 + c * 16 + lhi * 8];
      lacc = __builtin_amdgcn_mfma_f32_32x32x16_bf16(pa, vones, lacc, 0, 0, 0);
      oacc0 = __builtin_amdgcn_mfma_f32_32x32x16_bf16(pa, vf0, oacc0, 0, 0, 0);
      oacc1 = __builtin_amdgcn_mfma_f32_32x32x16_bf16(pa, vf1, oacc1, 0, 0, 0);
    }

    // stage tile kt+1 into the other buffer, then single barrier
    if (kt + 1 < SEQ / KBLK) {
#pragma unroll
      for (int i = 0; i < 2; ++i) {
        int s = tid + i * 256;
        *(bf16x8*)&Ks[cur ^ 1][s >> 3][(s & 7) * 8] = kreg[i];
        *(bf16x8*)&Vs[cur ^ 1][s >> 3][(s & 7) * 8] = vreg[i];
      }
      __syncthreads();
    }
  }

  // epilogue: normalize, write O in (B,T,H*D) bf16.
#pragma unroll
  for (int r = 0; r < 16; ++r) {
    int qrow = (r & 3) + 8 * (r >> 2) + 4 * lhi;
    int t = qi * QBLK + wid * 32 + qrow;
    float inv = 1.0f / lacc[r];
    size_t base = ((size_t)(b * SEQ + t)) * EMBED + h * HDIM;
    Ob[base + l31]      = f2bf(oacc0[r] * inv);
    Ob[base + 32 + l31] = f2bf(oacc1[r] * inv);
  }
}

// ---------------------------------------------------------------------------
// Output projection, 64x128 tile, BK=64 + XOR chunk-swizzle, double-buffered
// single-barrier loop. LDS 48 KB (grid 512 = 2 blocks/CU).
// ---------------------------------------------------------------------------
__global__ __launch_bounds__(256) void out_gemm(
    const short* __restrict__ A, const short* __restrict__ Wob,
    const float* __restrict__ bo, float* __restrict__ C)
{
  __shared__ short As[2][64][64];    // 2 x 8 KB
  __shared__ short Bs[2][128][64];   // 2 x 16 KB
  int tid = threadIdx.x;
  int lane = tid & 63, wid = tid >> 6;
  int bm = blockIdx.x >> 3, bn = blockIdx.x & 7;   // 64 x 8

  f32x4 acc[8] = {};
  const short* Abase = A + (size_t)bm * 64 * EMBED;
  const short* Bbase = Wob + (size_t)bn * 128 * EMBED;
  char* AsB = (char*)&As[0][0][0];
  char* BsB = (char*)&Bs[0][0][0];
  const int ATSZ = 64 * 64 * 2;      // 8192 B
  const int BTSZ = 128 * 64 * 2;     // 16384 B

  // prologue: stage tile 0 into buffer 0
#pragma unroll
  for (int i = 0; i < 2; ++i) {
    int s = tid + i * 256;           // 512 chunks (A tile 64x64)
    int row = s >> 3, c = s & 7;
    int cs = c ^ (row & 7);
    gload_lds16(&Abase[(size_t)row * EMBED + cs * 8],
                AsB + i * 4096 + wid * 1024 + lane * 16);
  }
#pragma unroll
  for (int i = 0; i < 4; ++i) {
    int s = tid + i * 256;           // 1024 chunks (B tile 128x64)
    int row = s >> 3, c = s & 7;
    int cs = c ^ (row & 7);
    gload_lds16(&Bbase[(size_t)row * EMBED + cs * 8],
                BsB + i * 4096 + wid * 1024 + lane * 16);
  }
  __syncthreads();

  for (int kt = 0; kt < EMBED / 64; ++kt) {
    int cur = kt & 1;
    if (kt + 1 < EMBED / 64) {
#pragma unroll
      for (int i = 0; i < 2; ++i) {
        int s = tid + i * 256;
        int row = s >> 3, c = s & 7;
        int cs = c ^ (row & 7);
        gload_lds16(&Abase[(size_t)row * EMBED + (kt + 1) * 64 + cs * 8],
                    AsB + (cur ^ 1) * ATSZ + i * 4096 + wid * 1024 + lane * 16);
      }
#pragma unroll
      for (int i = 0; i < 4; ++i) {
        int s = tid + i * 256;
        int row = s >> 3, c = s & 7;
        int cs = c ^ (row & 7);
        gload_lds16(&Bbase[(size_t)row * EMBED + (kt + 1) * 64 + cs * 8],
                    BsB + (cur ^ 1) * BTSZ + i * 4096 + wid * 1024 + lane * 16);
      }
    }

#pragma unroll
    for (int kk = 0; kk < 2; ++kk) {
      int cp = ((kk * 4 + (lane >> 4)) ^ (lane & 7)) * 8;
      bf16x8 af = *(const bf16x8*)&As[cur][wid * 16 + (lane & 15)][cp];
#pragma unroll
      for (int nf = 0; nf < 8; ++nf) {
        bf16x8 bfr = *(const bf16x8*)&Bs[cur][nf * 16 + (lane & 15)][cp];
        acc[nf] = __builtin_amdgcn_mfma_f32_16x16x32_bf16(af, bfr, acc[nf], 0, 0, 0);
      }
    }
    __syncthreads();
  }

#pragma unroll
  for (int nf = 0; nf < 8; ++nf) {
    int col = bn * 128 + nf * 16 + (lane & 15);
    float bb = bo[col];
    int row0 = bm * 64 + wid * 16 + ((lane >> 4) << 2);
#pragma unroll
    for (int r = 0; r < 4; ++r)
      C[(size_t)(row0 + r) * EMBED + col] = acc[nf][r] + bb;
  }
}

extern "C" void kernel_launch(void* const* d_in, const int* in_sizes, int n_in,
                              void* d_out, int out_size, void* d_ws, size_t ws_size,
                              hipStream_t stream) {
  const float* x  = (const float*)d_in[0];
  const float* Wq = (const float*)d_in[1];
  const float* bq = (const float*)d_in[2];
  const float* Wk = (const float*)d_in[3];
  const float* bk = (const float*)d_in[4];
  const float* Wv = (const float*)d_in[5];
  const float* bv = (const float*)d_in[6];
  const float* Wo = (const float*)d_in[7];
  const float* bo = (const float*)d_in[8];
  float* out = (float*)d_out;
  char* ws = (char*)d_ws;

  const size_t MB = 1u << 20;
  short* Qb  = (short*)(ws);                 // 8 MiB
  short* Kb  = (short*)(ws + 8 * MB);        // 8 MiB
  short* Vb  = (short*)(ws + 16 * MB);       // 8 MiB
  short* XOb = (short*)(ws + 24 * MB);       // 8 MiB: xb during proj, Ob after attn
  short* Wqb = (short*)(ws + 32 * MB);
  short* Wkb = (short*)(ws + 34 * MB);
  short* Wvb = (short*)(ws + 36 * MB);
  short* Wob = (short*)(ws + 38 * MB);
  f32x2* tab = (f32x2*)(ws + 40 * MB);       // 512 KiB RoPE table

  cvt_bf16<<<dim3(8448), dim3(256), 0, stream>>>(x, Wq, Wk, Wv, Wo, XOb, Wqb, Wkb, Wvb, Wob, tab);
  qkv_gemm<<<dim3(32 * 24), dim3(256), 0, stream>>>(XOb, Wqb, Wkb, Wvb, bq, bk, bv, tab, Qb, Kb, Vb);
  attn_kernel<<<dim3(BATCH * HEADS * (SEQ / QBLK)), dim3(256), 0, stream>>>(Qb, Kb, Vb, XOb);
  out_gemm<<<dim3(64 * 8), dim3(256), 0, stream>>>(XOb, Wob, bo, out);
}